// Round 1
// baseline (145.090 us; speedup 1.0000x reference)
//
#include <hip/hip_runtime.h>

// Problem constants (fixed by the reference): Q=4096 queries, N=65536 train, D=32.
#define QN 4096
#define NN 65536
#define DD 32

typedef __attribute__((ext_vector_type(8))) _Float16 half8;
typedef __attribute__((ext_vector_type(4))) _Float16 half4v;
typedef __attribute__((ext_vector_type(4))) float floatx4;

#define LOG2E 1.4426950408889634f
#define HALF_D_LOG_2PI 29.40603306254953f   // 16 * ln(2*pi)

// ---------------------------------------------------------------------------
// Workspace layout (bytes):
//   Xh    @ 0        : QN*DD*2 = 262144   (_Float16, X * log2(e))
//   Xth   @ 262144   : NN*DD*2 = 4194304  (_Float16, X_train unscaled)
//   c     @ 4456448  : NN*4    = 262144   (w_j * exp(-||y_j||^2/2))
//   qn    @ 4718592  : QN*4    = 16384    (||x_i||^2 / 2)
//   S     @ 4734976  : QN*4    = 16384    (accumulators; memset 0 each call)
//   sumw  @ 4751360  : 4
// ---------------------------------------------------------------------------

__global__ void prep_q(const float* __restrict__ X, _Float16* __restrict__ Xh,
                       float* __restrict__ qn) {
    int tid  = blockIdx.x * blockDim.x + threadIdx.x;   // QN*8 threads
    int row  = tid >> 3;
    int part = tid & 7;
    const float4 v = ((const float4*)X)[row * 8 + part];
    float nrm = v.x * v.x + v.y * v.y + v.z * v.z + v.w * v.w;
    nrm += __shfl_xor(nrm, 1);
    nrm += __shfl_xor(nrm, 2);
    nrm += __shfl_xor(nrm, 4);
    half4v h = { (_Float16)(v.x * LOG2E), (_Float16)(v.y * LOG2E),
                 (_Float16)(v.z * LOG2E), (_Float16)(v.w * LOG2E) };
    *(half4v*)(Xh + row * DD + part * 4) = h;
    if (part == 0) qn[row] = 0.5f * nrm;
}

__global__ void prep_t(const float* __restrict__ Xt, const float* __restrict__ w,
                       _Float16* __restrict__ Xth, float* __restrict__ c) {
    int tid  = blockIdx.x * blockDim.x + threadIdx.x;   // NN*8 threads
    int row  = tid >> 3;
    int part = tid & 7;
    const float4 v = ((const float4*)Xt)[row * 8 + part];
    float nrm = v.x * v.x + v.y * v.y + v.z * v.z + v.w * v.w;
    nrm += __shfl_xor(nrm, 1);
    nrm += __shfl_xor(nrm, 2);
    nrm += __shfl_xor(nrm, 4);
    half4v h = { (_Float16)v.x, (_Float16)v.y, (_Float16)v.z, (_Float16)v.w };
    *(half4v*)(Xth + row * DD + part * 4) = h;
    // c_j = w_j * exp(-||y_j||^2 / 2), computed in natural units via exp2
    if (part == 0) c[row] = w[row] * exp2f(-0.5f * LOG2E * nrm);
}

__global__ void sum_w(const float* __restrict__ w, float* __restrict__ sumw) {
    float v = 0.f;
    for (int i = blockIdx.x * blockDim.x + threadIdx.x; i < NN;
         i += gridDim.x * blockDim.x)
        v += w[i];
    #pragma unroll
    for (int o = 1; o < 64; o <<= 1) v += __shfl_xor(v, o);
    __shared__ float red[4];
    if ((threadIdx.x & 63) == 0) red[threadIdx.x >> 6] = v;
    __syncthreads();
    if (threadIdx.x == 0) atomicAdd(sumw, red[0] + red[1] + red[2] + red[3]);
}

// Main fused kernel: per wave, 64 queries x (strip of 512 train points).
// Grid: (QN/256, 128). Block: 256 threads = 4 waves.
__global__ __launch_bounds__(256) void kde_main(
    const _Float16* __restrict__ Xh, const _Float16* __restrict__ Xth,
    const float* __restrict__ c, float* __restrict__ S) {
    const int lane   = threadIdx.x & 63;
    const int wave   = threadIdx.x >> 6;
    const int quad   = lane >> 4;
    const int l16    = lane & 15;
    const int m_base = blockIdx.x * 256 + wave * 64;
    const int n_beg  = blockIdx.y * 512;

    // A fragments: 4 tiles of 16 queries, resident for the whole strip.
    // A[m = lane&15][k = quad*8 + j], j = 0..7 contiguous -> one 16B load.
    half8 a[4];
    #pragma unroll
    for (int t = 0; t < 4; ++t)
        a[t] = *(const half8*)(Xh + (m_base + t * 16 + l16) * DD + quad * 8);

    float s[4][4] = {};
    const floatx4 zero = {0.f, 0.f, 0.f, 0.f};

    for (int n0 = n_beg; n0 < n_beg + 512; n0 += 16) {
        // B fragment: B[k][n = lane&15], k = quad*8 + j  (row n of X_train)
        half8 b = *(const half8*)(Xth + (n0 + l16) * DD + quad * 8);
        float cv = c[n0 + l16];   // C layout: col = lane&15 for all 4 regs
        #pragma unroll
        for (int t = 0; t < 4; ++t) {
            floatx4 g = __builtin_amdgcn_mfma_f32_16x16x32_f16(a[t], b, zero, 0, 0, 0);
            #pragma unroll
            for (int r = 0; r < 4; ++r)
                s[t][r] += cv * exp2f(g[r]);   // g already in log2 units
        }
    }

    // Reduce over the 16 columns (lanes sharing the same quad), then atomic.
    #pragma unroll
    for (int t = 0; t < 4; ++t) {
        #pragma unroll
        for (int r = 0; r < 4; ++r) {
            float v = s[t][r];
            v += __shfl_xor(v, 1);
            v += __shfl_xor(v, 2);
            v += __shfl_xor(v, 4);
            v += __shfl_xor(v, 8);
            if (l16 == 0)
                atomicAdd(&S[m_base + t * 16 + quad * 4 + r], v);
        }
    }
}

__global__ void finalize(const float* __restrict__ S, const float* __restrict__ qn,
                         const float* __restrict__ sumw, float* __restrict__ out) {
    int i = blockIdx.x * blockDim.x + threadIdx.x;
    out[i] = logf(S[i]) - qn[i] - HALF_D_LOG_2PI - logf(*sumw);
}

extern "C" void kernel_launch(void* const* d_in, const int* in_sizes, int n_in,
                              void* d_out, int out_size, void* d_ws, size_t ws_size,
                              hipStream_t stream) {
    const float* X  = (const float*)d_in[0];
    const float* Xt = (const float*)d_in[1];
    const float* w  = (const float*)d_in[2];
    float* out = (float*)d_out;

    char* ws = (char*)d_ws;
    _Float16* Xh   = (_Float16*)(ws);
    _Float16* Xth  = (_Float16*)(ws + 262144);
    float*    c    = (float*)(ws + 4456448);
    float*    qn   = (float*)(ws + 4718592);
    float*    S    = (float*)(ws + 4734976);
    float*    sumw = (float*)(ws + 4751360);

    // Zero S + sumw (contiguous region) — ws is poisoned 0xAA before each call.
    hipMemsetAsync(S, 0, QN * sizeof(float) + sizeof(float), stream);

    prep_q<<<QN * 8 / 256, 256, 0, stream>>>(X, Xh, qn);
    prep_t<<<NN * 8 / 256, 256, 0, stream>>>(Xt, w, Xth, c);
    sum_w<<<64, 256, 0, stream>>>(w, sumw);
    kde_main<<<dim3(QN / 256, 128), 256, 0, stream>>>(Xh, Xth, c, S);
    finalize<<<QN / 256, 256, 0, stream>>>(S, qn, sumw, out);
}

// Round 2
// 116.043 us; speedup vs baseline: 1.2503x; 1.2503x over previous
//
#include <hip/hip_runtime.h>

// Problem constants (fixed by the reference): Q=4096 queries, N=65536 train, D=32.
#define QN 4096
#define NN 65536
#define DD 32

typedef __attribute__((ext_vector_type(8))) _Float16 half8;
typedef __attribute__((ext_vector_type(4))) _Float16 half4v;
typedef __attribute__((ext_vector_type(4))) float floatx4;

#define LOG2E 1.4426950408889634f
#define HALF_D_LOG_2PI 29.40603306254953f   // 16 * ln(2*pi)

// ---------------------------------------------------------------------------
// Workspace layout (bytes):
//   Xh    @ 0        : QN*DD*2 = 262144   (_Float16, X * log2(e))
//   Xth   @ 262144   : NN*DD*2 = 4194304  (_Float16, X_train unscaled)
//   c     @ 4456448  : NN*4    = 262144   (w_j * exp(-||y_j||^2/2))
//   qn    @ 4718592  : QN*4    = 16384    (||x_i||^2 / 2, nat units)
//   S     @ 4734976  : QN*4    = 16384    (accumulators; memset 0 each call)
//   sumw  @ 4751360  : 4
// ---------------------------------------------------------------------------

// Fused prep: blocks [0,128) convert X, [128,2176) convert X_train + c,
// [2176,2240) reduce sum(w). One dispatch instead of three.
__global__ __launch_bounds__(256) void prep_all(
    const float* __restrict__ X, const float* __restrict__ Xt,
    const float* __restrict__ w, _Float16* __restrict__ Xh,
    float* __restrict__ qn, _Float16* __restrict__ Xth,
    float* __restrict__ c, float* __restrict__ sumw) {
    const int b = blockIdx.x;
    if (b < 128) {                       // ---- prep X: QN rows, 8 lanes/row
        int tid  = b * 256 + threadIdx.x;
        int row  = tid >> 3;
        int part = tid & 7;
        const float4 v = ((const float4*)X)[row * 8 + part];
        float nrm = v.x * v.x + v.y * v.y + v.z * v.z + v.w * v.w;
        nrm += __shfl_xor(nrm, 1);
        nrm += __shfl_xor(nrm, 2);
        nrm += __shfl_xor(nrm, 4);
        half4v h = { (_Float16)(v.x * LOG2E), (_Float16)(v.y * LOG2E),
                     (_Float16)(v.z * LOG2E), (_Float16)(v.w * LOG2E) };
        *(half4v*)(Xh + row * DD + part * 4) = h;
        if (part == 0) qn[row] = 0.5f * nrm;
    } else if (b < 2176) {               // ---- prep X_train: NN rows
        int tid  = (b - 128) * 256 + threadIdx.x;
        int row  = tid >> 3;
        int part = tid & 7;
        const float4 v = ((const float4*)Xt)[row * 8 + part];
        float nrm = v.x * v.x + v.y * v.y + v.z * v.z + v.w * v.w;
        nrm += __shfl_xor(nrm, 1);
        nrm += __shfl_xor(nrm, 2);
        nrm += __shfl_xor(nrm, 4);
        half4v h = { (_Float16)v.x, (_Float16)v.y, (_Float16)v.z, (_Float16)v.w };
        *(half4v*)(Xth + row * DD + part * 4) = h;
        // c_j = w_j * exp(-||y_j||^2 / 2) via exp2
        if (part == 0)
            c[row] = w[row] * __builtin_amdgcn_exp2f(-0.5f * LOG2E * nrm);
    } else {                             // ---- sum(w): 64 blocks
        int bid = b - 2176;
        float v = 0.f;
        for (int i = bid * 256 + threadIdx.x; i < NN; i += 64 * 256)
            v += w[i];
        #pragma unroll
        for (int o = 1; o < 64; o <<= 1) v += __shfl_xor(v, o);
        __shared__ float red[4];
        if ((threadIdx.x & 63) == 0) red[threadIdx.x >> 6] = v;
        __syncthreads();
        if (threadIdx.x == 0) atomicAdd(sumw, red[0] + red[1] + red[2] + red[3]);
    }
}

// Main fused kernel: per wave, 64 queries x (strip of 512 train points).
// Grid: (QN/256, 128). Block: 256 threads = 4 waves.
__global__ __launch_bounds__(256) void kde_main(
    const _Float16* __restrict__ Xh, const _Float16* __restrict__ Xth,
    const float* __restrict__ c, float* __restrict__ S) {
    const int lane   = threadIdx.x & 63;
    const int wave   = threadIdx.x >> 6;
    const int quad   = lane >> 4;
    const int l16    = lane & 15;
    const int m_base = blockIdx.x * 256 + wave * 64;
    const int n_beg  = blockIdx.y * 512;

    // A fragments: 4 tiles of 16 queries, resident for the whole strip.
    // A[m = lane&15][k = quad*8 + j], j contiguous -> one 16B load each.
    half8 a[4];
    #pragma unroll
    for (int t = 0; t < 4; ++t)
        a[t] = *(const half8*)(Xh + (m_base + t * 16 + l16) * DD + quad * 8);

    float s[4][4] = {};
    const floatx4 zero = {0.f, 0.f, 0.f, 0.f};

    // Per-lane pointers; advance by 16 rows per iteration (2 VALU adds).
    const _Float16* bp = Xth + (size_t)(n_beg + l16) * DD + quad * 8;
    const float*    cp = c + n_beg + l16;

    for (int it = 0; it < 32; ++it) {
        half8 bfrag = *(const half8*)bp;   // B[k][n=l16], k = quad*8+j
        float cv    = *cp;                 // C layout: col = l16 for all regs
        #pragma unroll
        for (int t = 0; t < 4; ++t) {
            floatx4 g = __builtin_amdgcn_mfma_f32_16x16x32_f16(a[t], bfrag, zero, 0, 0, 0);
            #pragma unroll
            for (int r = 0; r < 4; ++r)
                s[t][r] += cv * __builtin_amdgcn_exp2f(g[r]);  // g in log2 units
        }
        bp += 16 * DD;
        cp += 16;
    }

    // Reduce over the 16 columns (lanes sharing the same quad), then atomic.
    #pragma unroll
    for (int t = 0; t < 4; ++t) {
        #pragma unroll
        for (int r = 0; r < 4; ++r) {
            float v = s[t][r];
            v += __shfl_xor(v, 1);
            v += __shfl_xor(v, 2);
            v += __shfl_xor(v, 4);
            v += __shfl_xor(v, 8);
            if (l16 == 0)
                atomicAdd(&S[m_base + t * 16 + quad * 4 + r], v);
        }
    }
}

__global__ void finalize(const float* __restrict__ S, const float* __restrict__ qn,
                         const float* __restrict__ sumw, float* __restrict__ out) {
    int i = blockIdx.x * blockDim.x + threadIdx.x;
    out[i] = logf(S[i]) - qn[i] - HALF_D_LOG_2PI - logf(*sumw);
}

extern "C" void kernel_launch(void* const* d_in, const int* in_sizes, int n_in,
                              void* d_out, int out_size, void* d_ws, size_t ws_size,
                              hipStream_t stream) {
    const float* X  = (const float*)d_in[0];
    const float* Xt = (const float*)d_in[1];
    const float* w  = (const float*)d_in[2];
    float* out = (float*)d_out;

    char* ws = (char*)d_ws;
    _Float16* Xh   = (_Float16*)(ws);
    _Float16* Xth  = (_Float16*)(ws + 262144);
    float*    c    = (float*)(ws + 4456448);
    float*    qn   = (float*)(ws + 4718592);
    float*    S    = (float*)(ws + 4734976);
    float*    sumw = (float*)(ws + 4751360);

    // Zero S + sumw (contiguous) — ws is poisoned 0xAA before each timed call.
    hipMemsetAsync(S, 0, QN * sizeof(float) + sizeof(float), stream);

    prep_all<<<2240, 256, 0, stream>>>(X, Xt, w, Xh, qn, Xth, c, sumw);
    kde_main<<<dim3(QN / 256, 128), 256, 0, stream>>>(Xh, Xth, c, S);
    finalize<<<QN / 256, 256, 0, stream>>>(S, qn, sumw, out);
}